// Round 5
// baseline (158.693 us; speedup 1.0000x reference)
//
#include <hip/hip_runtime.h>

#define D 128
#define KNEG 5
#define BLOCK 256

typedef _Float16 h2 __attribute__((ext_vector_type(2)));
typedef _Float16 h8 __attribute__((ext_vector_type(8)));
typedef float f2 __attribute__((ext_vector_type(2)));

#if defined(__has_builtin)
#if __has_builtin(__builtin_amdgcn_cvt_pk_fp8_f32) && __has_builtin(__builtin_amdgcn_cvt_pk_f32_fp8)
#define HAVE_FP8 1
#endif
#endif

// ---- helpers ---------------------------------------------------------------

// stable fast softplus: max(z,0) + log(1+exp(-|z|)); exp arg <= 0, log arg in (1,2]
__device__ __forceinline__ float softplus_fast(float z) {
    return fmaxf(z, 0.0f) + __logf(1.0f + __expf(-fabsf(z)));
}

__device__ __forceinline__ float dot2_acc(h2 a, h2 b, float acc) {
#if defined(__has_builtin)
#if __has_builtin(__builtin_amdgcn_fdot2)
    return __builtin_amdgcn_fdot2(a, b, acc, false);
#else
    return fmaf((float)a[0], (float)b[0], fmaf((float)a[1], (float)b[1], acc));
#endif
#else
    return fmaf((float)a[0], (float)b[0], fmaf((float)a[1], (float)b[1], acc));
#endif
}

__device__ __forceinline__ float dot_h8(h8 a, h8 b) {
    float acc = 0.0f;
    acc = dot2_acc(__builtin_shufflevector(a, a, 0, 1), __builtin_shufflevector(b, b, 0, 1), acc);
    acc = dot2_acc(__builtin_shufflevector(a, a, 2, 3), __builtin_shufflevector(b, b, 2, 3), acc);
    acc = dot2_acc(__builtin_shufflevector(a, a, 4, 5), __builtin_shufflevector(b, b, 4, 5), acc);
    acc = dot2_acc(__builtin_shufflevector(a, a, 6, 7), __builtin_shufflevector(b, b, 6, 7), acc);
    return acc;
}

#ifdef HAVE_FP8
// decode 8 packed e4m3 (int2) into 4 float2
__device__ __forceinline__ void cvt8(int2 w, f2& a, f2& b, f2& c, f2& d) {
    a = __builtin_amdgcn_cvt_pk_f32_fp8(w.x, false);
    b = __builtin_amdgcn_cvt_pk_f32_fp8(w.x, true);
    c = __builtin_amdgcn_cvt_pk_f32_fp8(w.y, false);
    d = __builtin_amdgcn_cvt_pk_f32_fp8(w.y, true);
}

__device__ __forceinline__ float dot8q(f2 v01, f2 v23, f2 v45, f2 v67, int2 w) {
    f2 b01, b23, b45, b67;
    cvt8(w, b01, b23, b45, b67);
    float s0 = v01[0] * b01[0];
    float s1 = v01[1] * b01[1];
    s0 = fmaf(v23[0], b23[0], s0);
    s1 = fmaf(v23[1], b23[1], s1);
    s0 = fmaf(v45[0], b45[0], s0);
    s1 = fmaf(v45[1], b45[1], s1);
    s0 = fmaf(v67[0], b67[0], s0);
    s1 = fmaf(v67[1], b67[1], s1);
    return s0 + s1;
}
#endif

// ---- kernels ---------------------------------------------------------------

__global__ void zero_ws_kernel(double* ws) { *ws = 0.0; }

#ifdef HAVE_FP8
// fp32 -> fp8 e4m3 row compression; 8 elements/thread; also zeroes the accumulator
__global__ __launch_bounds__(BLOCK) void cvt_fp8_kernel(const float* __restrict__ x,
                                                        int2* __restrict__ xq,
                                                        double* __restrict__ ws, int n8)
{
    if (blockIdx.x == 0 && threadIdx.x == 0) *ws = 0.0;
    int i = blockIdx.x * BLOCK + threadIdx.x;
    const int stride = gridDim.x * BLOCK;
    for (; i < n8; i += stride) {
        const float4* p = reinterpret_cast<const float4*>(x) + 2 * (size_t)i;
        const float4 f0 = p[0], f1 = p[1];
        int lo = 0, hi = 0;
        lo = __builtin_amdgcn_cvt_pk_fp8_f32(f0.x, f0.y, lo, false);
        lo = __builtin_amdgcn_cvt_pk_fp8_f32(f0.z, f0.w, lo, true);
        hi = __builtin_amdgcn_cvt_pk_fp8_f32(f1.x, f1.y, hi, false);
        hi = __builtin_amdgcn_cvt_pk_fp8_f32(f1.z, f1.w, hi, true);
        xq[i] = make_int2(lo, hi);
    }
}

// main kernel, fp8 rows: 16 lanes/edge, lane holds 8 cols (8 B); row = one 128 B line
__global__ __launch_bounds__(BLOCK) void neg_loss_fp8(
    const int2* __restrict__ xq,    // [N, 16] int2; row = 128 B
    const int* __restrict__ ei,     // [2, E]
    const int* __restrict__ nei,    // [K, E]
    double* __restrict__ ws, int E)
{
    const int l    = threadIdx.x & 15;
    const int grp  = blockIdx.x * (BLOCK / 16) + (threadIdx.x >> 4);
    const int ngrp = gridDim.x * (BLOCK / 16);

    float local = 0.0f;

    for (int e = grp; e < E; e += ngrp) {
        const int src = ei[e];
        const int i0 = ei[E + e];
        const int i1 = nei[e];
        const int i2 = nei[(size_t)E * 1 + e];
        const int i3 = nei[(size_t)E * 2 + e];
        const int i4 = nei[(size_t)E * 3 + e];
        const int i5 = nei[(size_t)E * 4 + e];

        const int2 wv = xq[(size_t)src * 16 + l];
        const int2 w0 = xq[(size_t)i0 * 16 + l];
        const int2 w1 = xq[(size_t)i1 * 16 + l];
        const int2 w2 = xq[(size_t)i2 * 16 + l];
        const int2 w3 = xq[(size_t)i3 * 16 + l];
        const int2 w4 = xq[(size_t)i4 * 16 + l];
        const int2 w5 = xq[(size_t)i5 * 16 + l];

        f2 v01, v23, v45, v67;
        cvt8(wv, v01, v23, v45, v67);   // src slice decoded once, reused 6x

        float a0 = dot8q(v01, v23, v45, v67, w0);
        float a1 = dot8q(v01, v23, v45, v67, w1);
        float a2 = dot8q(v01, v23, v45, v67, w2);
        float a3 = dot8q(v01, v23, v45, v67, w3);
        float a4 = dot8q(v01, v23, v45, v67, w4);
        float a5 = dot8q(v01, v23, v45, v67, w5);

        // butterfly over the 16-lane group (xor masks <16 stay in-group)
        #pragma unroll
        for (int off = 8; off > 0; off >>= 1) {
            a0 += __shfl_xor(a0, off);
            a1 += __shfl_xor(a1, off);
            a2 += __shfl_xor(a2, off);
            a3 += __shfl_xor(a3, off);
            a4 += __shfl_xor(a4, off);
            a5 += __shfl_xor(a5, off);
        }

        // lanes 0-5 each take one softplus term; positive logit uses softplus(-z)
        float z = -a0;
        if (l == 1) z = a1;
        else if (l == 2) z = a2;
        else if (l == 3) z = a3;
        else if (l == 4) z = a4;
        else if (l == 5) z = a5;
        if (l < 6) local += softplus_fast(z);
    }

    #pragma unroll
    for (int off = 32; off > 0; off >>= 1) local += __shfl_xor(local, off);

    __shared__ float sbuf[BLOCK / 64];
    const int wid = threadIdx.x >> 6;
    if ((threadIdx.x & 63) == 0) sbuf[wid] = local;
    __syncthreads();
    if (threadIdx.x == 0) {
        float s = 0.0f;
        #pragma unroll
        for (int i = 0; i < BLOCK / 64; ++i) s += sbuf[i];
        atomicAdd(ws, (double)s);
    }
}
#endif // HAVE_FP8

// fp16 path (proven round-3 kernel) — fallback if fp8 unavailable or ws too small
__global__ __launch_bounds__(BLOCK) void cvt_f16_kernel(const float* __restrict__ x,
                                                        h8* __restrict__ xh,
                                                        double* __restrict__ ws, int n8)
{
    if (blockIdx.x == 0 && threadIdx.x == 0) *ws = 0.0;
    int i = blockIdx.x * BLOCK + threadIdx.x;
    const int stride = gridDim.x * BLOCK;
    for (; i < n8; i += stride) {
        const float4* p = reinterpret_cast<const float4*>(x) + 2 * (size_t)i;
        const float4 f0 = p[0], f1 = p[1];
        h8 o;
        o[0] = (_Float16)f0.x; o[1] = (_Float16)f0.y; o[2] = (_Float16)f0.z; o[3] = (_Float16)f0.w;
        o[4] = (_Float16)f1.x; o[5] = (_Float16)f1.y; o[6] = (_Float16)f1.z; o[7] = (_Float16)f1.w;
        xh[i] = o;
    }
}

__global__ __launch_bounds__(BLOCK) void neg_loss_f16(
    const h8* __restrict__ xh,      // [N, 16] h8; row = 256 B
    const int* __restrict__ ei,
    const int* __restrict__ nei,
    double* __restrict__ ws, int E)
{
    const int l    = threadIdx.x & 15;
    const int grp  = blockIdx.x * (BLOCK / 16) + (threadIdx.x >> 4);
    const int ngrp = gridDim.x * (BLOCK / 16);

    float local = 0.0f;

    for (int e = grp; e < E; e += ngrp) {
        const int src = ei[e];
        const int i0 = ei[E + e];
        const int i1 = nei[e];
        const int i2 = nei[(size_t)E * 1 + e];
        const int i3 = nei[(size_t)E * 2 + e];
        const int i4 = nei[(size_t)E * 3 + e];
        const int i5 = nei[(size_t)E * 4 + e];

        const h8 vi = xh[(size_t)src * 16 + l];
        const h8 u0 = xh[(size_t)i0 * 16 + l];
        const h8 u1 = xh[(size_t)i1 * 16 + l];
        const h8 u2 = xh[(size_t)i2 * 16 + l];
        const h8 u3 = xh[(size_t)i3 * 16 + l];
        const h8 u4 = xh[(size_t)i4 * 16 + l];
        const h8 u5 = xh[(size_t)i5 * 16 + l];

        float a0 = dot_h8(vi, u0);
        float a1 = dot_h8(vi, u1);
        float a2 = dot_h8(vi, u2);
        float a3 = dot_h8(vi, u3);
        float a4 = dot_h8(vi, u4);
        float a5 = dot_h8(vi, u5);

        #pragma unroll
        for (int off = 8; off > 0; off >>= 1) {
            a0 += __shfl_xor(a0, off);
            a1 += __shfl_xor(a1, off);
            a2 += __shfl_xor(a2, off);
            a3 += __shfl_xor(a3, off);
            a4 += __shfl_xor(a4, off);
            a5 += __shfl_xor(a5, off);
        }

        float z = -a0;
        if (l == 1) z = a1;
        else if (l == 2) z = a2;
        else if (l == 3) z = a3;
        else if (l == 4) z = a4;
        else if (l == 5) z = a5;
        if (l < 6) local += softplus_fast(z);
    }

    #pragma unroll
    for (int off = 32; off > 0; off >>= 1) local += __shfl_xor(local, off);

    __shared__ float sbuf[BLOCK / 64];
    const int wid = threadIdx.x >> 6;
    if ((threadIdx.x & 63) == 0) sbuf[wid] = local;
    __syncthreads();
    if (threadIdx.x == 0) {
        float s = 0.0f;
        #pragma unroll
        for (int i = 0; i < BLOCK / 64; ++i) s += sbuf[i];
        atomicAdd(ws, (double)s);
    }
}

// fp32 fallback (ws too small for any compressed copy)
__global__ __launch_bounds__(BLOCK) void neg_loss_f32(
    const float* __restrict__ x,
    const int* __restrict__ ei,
    const int* __restrict__ nei,
    double* __restrict__ ws, int E)
{
    const int l    = threadIdx.x & 31;
    const int grp  = blockIdx.x * (BLOCK / 32) + (threadIdx.x >> 5);
    const int ngrp = gridDim.x * (BLOCK / 32);
    const int colb = l * 4;

    float local = 0.0f;

    for (int e = grp; e < E; e += ngrp) {
        const int src = ei[e];
        const int idx[6] = {ei[E + e], nei[e],
                            nei[(size_t)E * 1 + e], nei[(size_t)E * 2 + e],
                            nei[(size_t)E * 3 + e], nei[(size_t)E * 4 + e]};

        const float4 vi = *reinterpret_cast<const float4*>(x + (size_t)src * D + colb);
        float a[6];
        #pragma unroll
        for (int n = 0; n < 6; ++n) {
            const float4 u = *reinterpret_cast<const float4*>(x + (size_t)idx[n] * D + colb);
            a[n] = fmaf(vi.x, u.x, fmaf(vi.y, u.y, fmaf(vi.z, u.z, vi.w * u.w)));
        }

        #pragma unroll
        for (int off = 16; off > 0; off >>= 1) {
            #pragma unroll
            for (int n = 0; n < 6; ++n) a[n] += __shfl_xor(a[n], off);
        }

        float z = -a[0];
        if (l == 1) z = a[1];
        else if (l == 2) z = a[2];
        else if (l == 3) z = a[3];
        else if (l == 4) z = a[4];
        else if (l == 5) z = a[5];
        if (l < 6) local += softplus_fast(z);
    }

    #pragma unroll
    for (int off = 32; off > 0; off >>= 1) local += __shfl_xor(local, off);

    __shared__ float sbuf[BLOCK / 64];
    const int wid = threadIdx.x >> 6;
    if ((threadIdx.x & 63) == 0) sbuf[wid] = local;
    __syncthreads();
    if (threadIdx.x == 0) {
        float s = 0.0f;
        #pragma unroll
        for (int i = 0; i < BLOCK / 64; ++i) s += sbuf[i];
        atomicAdd(ws, (double)s);
    }
}

__global__ void finalize_kernel(const double* __restrict__ ws,
                                float* __restrict__ out, double count)
{
    *out = (float)(*ws / count);
}

// ---- launch ----------------------------------------------------------------

extern "C" void kernel_launch(void* const* d_in, const int* in_sizes, int n_in,
                              void* d_out, int out_size, void* d_ws, size_t ws_size,
                              hipStream_t stream)
{
    const float* x  = (const float*)d_in[0];
    const int*  ei  = (const int*)d_in[1];
    const int*  nei = (const int*)d_in[2];
    const int E  = in_sizes[1] / 2;
    const int ND = in_sizes[0];          // N*D elements of x

    double* ws = (double*)d_ws;
    float* out = (float*)d_out;

#ifdef HAVE_FP8
    const size_t need8 = 256 + (size_t)ND;
    if (ws_size >= need8) {
        int2* xq = (int2*)((char*)d_ws + 256);
        cvt_fp8_kernel<<<dim3(1024), dim3(BLOCK), 0, stream>>>(x, xq, ws, ND / 8);
        neg_loss_fp8<<<dim3(2048), dim3(BLOCK), 0, stream>>>(xq, ei, nei, ws, E);
        const double count = (double)E * (double)(KNEG + 1);
        finalize_kernel<<<dim3(1), dim3(1), 0, stream>>>(ws, out, count);
        return;
    }
#endif

    const size_t need16 = 256 + (size_t)ND * sizeof(_Float16);
    if (ws_size >= need16) {
        h8* xh = (h8*)((char*)d_ws + 256);
        cvt_f16_kernel<<<dim3(1024), dim3(BLOCK), 0, stream>>>(x, xh, ws, ND / 8);
        neg_loss_f16<<<dim3(2048), dim3(BLOCK), 0, stream>>>(xh, ei, nei, ws, E);
    } else {
        zero_ws_kernel<<<dim3(1), dim3(1), 0, stream>>>(ws);
        neg_loss_f32<<<dim3(2048), dim3(BLOCK), 0, stream>>>(x, ei, nei, ws, E);
    }

    const double count = (double)E * (double)(KNEG + 1);
    finalize_kernel<<<dim3(1), dim3(1), 0, stream>>>(ws, out, count);
}

// Round 6
// 105.412 us; speedup vs baseline: 1.5054x; 1.5054x over previous
//
#include <hip/hip_runtime.h>

#define D 128
#define KNEG 5
#define BLOCK 256

typedef float f2 __attribute__((ext_vector_type(2)));

// Device-pass-only HW fp8 builtin detection (host pass lacks amdgcn builtins;
// the launcher below does NOT depend on this macro).
#if defined(__HIP_DEVICE_COMPILE__)
#if __has_builtin(__builtin_amdgcn_cvt_pk_f32_fp8) && __has_builtin(__builtin_amdgcn_cvt_pk_fp8_f32)
#define FP8_HW 1
#endif
#endif

// ---- fp8 e4m3fn software fallback (bit-exact enough; dead code if FP8_HW) --

__device__ __forceinline__ float dec1_sw(unsigned b) {
    const unsigned s = b >> 7, e = (b >> 3) & 15, m = b & 7;
    float mag;
    if (e == 0) {
        mag = (float)m * 0x1p-9f;                     // subnormal: m * 2^-9
    } else {
        union { unsigned u; float f; } c;
        c.u = ((e + 120u) << 23) | (m << 20);          // (1+m/8) * 2^(e-7)
        mag = c.f;
    }
    return s ? -mag : mag;
}

__device__ __forceinline__ unsigned enc1_sw(float x) {
    union { float f; unsigned u; } c; c.f = x;
    const unsigned s = (c.u >> 31) << 7;
    float a = fabsf(x);
    if (!(a >= 0x1p-10f)) return s;                    // below half-min-subnormal (or NaN->0; inputs finite)
    if (a < 0x1p-6f) {                                 // subnormal grid: k * 2^-9
        unsigned m = (unsigned)rintf(a * 512.0f);
        if (m > 7) return s | (1u << 3);               // rounded up to first normal
        return s | m;
    }
    c.f = a;
    unsigned bits = c.u + 0x00080000u;                 // round-half-up at 3-bit mantissa
    int e = (int)(bits >> 23) - 120;
    unsigned m = (bits >> 20) & 7;
    if (e >= 16) return s | 0x7Eu;                     // clamp to max finite 448
    if (e <= 0) return s | (1u << 3);                  // can't really happen (a >= 2^-6)
    return s | ((unsigned)e << 3) | m;
}

// ---- fp8 pack/unpack (HW when available) -----------------------------------

__device__ __forceinline__ void cvt8(int2 w, f2& a, f2& b, f2& c, f2& d) {
#ifdef FP8_HW
    a = __builtin_amdgcn_cvt_pk_f32_fp8(w.x, false);
    b = __builtin_amdgcn_cvt_pk_f32_fp8(w.x, true);
    c = __builtin_amdgcn_cvt_pk_f32_fp8(w.y, false);
    d = __builtin_amdgcn_cvt_pk_f32_fp8(w.y, true);
#else
    a[0] = dec1_sw(w.x & 0xff);         a[1] = dec1_sw((w.x >> 8) & 0xff);
    b[0] = dec1_sw((w.x >> 16) & 0xff); b[1] = dec1_sw((unsigned)w.x >> 24);
    c[0] = dec1_sw(w.y & 0xff);         c[1] = dec1_sw((w.y >> 8) & 0xff);
    d[0] = dec1_sw((w.y >> 16) & 0xff); d[1] = dec1_sw((unsigned)w.y >> 24);
#endif
}

__device__ __forceinline__ int pack4(float x, float y, float z, float w) {
#ifdef FP8_HW
    int r = 0;
    r = __builtin_amdgcn_cvt_pk_fp8_f32(x, y, r, false);  // bytes 0,1
    r = __builtin_amdgcn_cvt_pk_fp8_f32(z, w, r, true);   // bytes 2,3
    return r;
#else
    return (int)(enc1_sw(x) | (enc1_sw(y) << 8) | (enc1_sw(z) << 16) | (enc1_sw(w) << 24));
#endif
}

// ---- misc helpers ----------------------------------------------------------

// stable fast softplus: max(z,0) + log(1+exp(-|z|)); exp arg <= 0, log arg in (1,2]
__device__ __forceinline__ float softplus_fast(float z) {
    return fmaxf(z, 0.0f) + __logf(1.0f + __expf(-fabsf(z)));
}

__device__ __forceinline__ float dot8q(f2 v01, f2 v23, f2 v45, f2 v67, int2 w) {
    f2 b01, b23, b45, b67;
    cvt8(w, b01, b23, b45, b67);
    float s0 = v01[0] * b01[0];
    float s1 = v01[1] * b01[1];
    s0 = fmaf(v23[0], b23[0], s0);
    s1 = fmaf(v23[1], b23[1], s1);
    s0 = fmaf(v45[0], b45[0], s0);
    s1 = fmaf(v45[1], b45[1], s1);
    s0 = fmaf(v67[0], b67[0], s0);
    s1 = fmaf(v67[1], b67[1], s1);
    return s0 + s1;
}

// ---- kernels ---------------------------------------------------------------

__global__ void zero_ws_kernel(double* ws) { *ws = 0.0; }

// fp32 -> fp8 e4m3 row compression; 8 elements/thread; also zeroes the accumulator
__global__ __launch_bounds__(BLOCK) void cvt_fp8_kernel(const float* __restrict__ x,
                                                        int2* __restrict__ xq,
                                                        double* __restrict__ ws, int n8)
{
    if (blockIdx.x == 0 && threadIdx.x == 0) *ws = 0.0;
    int i = blockIdx.x * BLOCK + threadIdx.x;
    const int stride = gridDim.x * BLOCK;
    for (; i < n8; i += stride) {
        const float4* p = reinterpret_cast<const float4*>(x) + 2 * (size_t)i;
        const float4 f0 = p[0], f1 = p[1];
        int2 o;
        o.x = pack4(f0.x, f0.y, f0.z, f0.w);
        o.y = pack4(f1.x, f1.y, f1.z, f1.w);
        xq[i] = o;
    }
}

// main kernel, fp8 rows: 16 lanes/edge, lane holds 8 cols (8 B); row = one 128 B block
__global__ __launch_bounds__(BLOCK) void neg_loss_fp8(
    const int2* __restrict__ xq,    // [N, 16] int2; row = 128 B
    const int* __restrict__ ei,     // [2, E]
    const int* __restrict__ nei,    // [K, E]
    double* __restrict__ ws, int E)
{
    const int l    = threadIdx.x & 15;
    const int grp  = blockIdx.x * (BLOCK / 16) + (threadIdx.x >> 4);
    const int ngrp = gridDim.x * (BLOCK / 16);

    float local = 0.0f;

    for (int e = grp; e < E; e += ngrp) {
        const int src = ei[e];
        const int i0 = ei[E + e];
        const int i1 = nei[e];
        const int i2 = nei[(size_t)E * 1 + e];
        const int i3 = nei[(size_t)E * 2 + e];
        const int i4 = nei[(size_t)E * 3 + e];
        const int i5 = nei[(size_t)E * 4 + e];

        const int2 wv = xq[(size_t)src * 16 + l];
        const int2 w0 = xq[(size_t)i0 * 16 + l];
        const int2 w1 = xq[(size_t)i1 * 16 + l];
        const int2 w2 = xq[(size_t)i2 * 16 + l];
        const int2 w3 = xq[(size_t)i3 * 16 + l];
        const int2 w4 = xq[(size_t)i4 * 16 + l];
        const int2 w5 = xq[(size_t)i5 * 16 + l];

        f2 v01, v23, v45, v67;
        cvt8(wv, v01, v23, v45, v67);   // src slice decoded once, reused 6x

        float a0 = dot8q(v01, v23, v45, v67, w0);
        float a1 = dot8q(v01, v23, v45, v67, w1);
        float a2 = dot8q(v01, v23, v45, v67, w2);
        float a3 = dot8q(v01, v23, v45, v67, w3);
        float a4 = dot8q(v01, v23, v45, v67, w4);
        float a5 = dot8q(v01, v23, v45, v67, w5);

        // butterfly over the 16-lane group (xor masks <16 stay in-group)
        #pragma unroll
        for (int off = 8; off > 0; off >>= 1) {
            a0 += __shfl_xor(a0, off);
            a1 += __shfl_xor(a1, off);
            a2 += __shfl_xor(a2, off);
            a3 += __shfl_xor(a3, off);
            a4 += __shfl_xor(a4, off);
            a5 += __shfl_xor(a5, off);
        }

        // lanes 0-5 each take one softplus term; positive logit uses softplus(-z)
        float z = -a0;
        if (l == 1) z = a1;
        else if (l == 2) z = a2;
        else if (l == 3) z = a3;
        else if (l == 4) z = a4;
        else if (l == 5) z = a5;
        if (l < 6) local += softplus_fast(z);
    }

    #pragma unroll
    for (int off = 32; off > 0; off >>= 1) local += __shfl_xor(local, off);

    __shared__ float sbuf[BLOCK / 64];
    const int wid = threadIdx.x >> 6;
    if ((threadIdx.x & 63) == 0) sbuf[wid] = local;
    __syncthreads();
    if (threadIdx.x == 0) {
        float s = 0.0f;
        #pragma unroll
        for (int i = 0; i < BLOCK / 64; ++i) s += sbuf[i];
        atomicAdd(ws, (double)s);
    }
}

// fp32 fallback (only if ws can't hold the 12.8 MB fp8 table)
__global__ __launch_bounds__(BLOCK) void neg_loss_f32(
    const float* __restrict__ x,
    const int* __restrict__ ei,
    const int* __restrict__ nei,
    double* __restrict__ ws, int E)
{
    const int l    = threadIdx.x & 31;
    const int grp  = blockIdx.x * (BLOCK / 32) + (threadIdx.x >> 5);
    const int ngrp = gridDim.x * (BLOCK / 32);
    const int colb = l * 4;

    float local = 0.0f;

    for (int e = grp; e < E; e += ngrp) {
        const int src = ei[e];
        const int idx[6] = {ei[E + e], nei[e],
                            nei[(size_t)E * 1 + e], nei[(size_t)E * 2 + e],
                            nei[(size_t)E * 3 + e], nei[(size_t)E * 4 + e]};

        const float4 vi = *reinterpret_cast<const float4*>(x + (size_t)src * D + colb);
        float a[6];
        #pragma unroll
        for (int n = 0; n < 6; ++n) {
            const float4 u = *reinterpret_cast<const float4*>(x + (size_t)idx[n] * D + colb);
            a[n] = fmaf(vi.x, u.x, fmaf(vi.y, u.y, fmaf(vi.z, u.z, vi.w * u.w)));
        }

        #pragma unroll
        for (int off = 16; off > 0; off >>= 1) {
            #pragma unroll
            for (int n = 0; n < 6; ++n) a[n] += __shfl_xor(a[n], off);
        }

        float z = -a[0];
        if (l == 1) z = a[1];
        else if (l == 2) z = a[2];
        else if (l == 3) z = a[3];
        else if (l == 4) z = a[4];
        else if (l == 5) z = a[5];
        if (l < 6) local += softplus_fast(z);
    }

    #pragma unroll
    for (int off = 32; off > 0; off >>= 1) local += __shfl_xor(local, off);

    __shared__ float sbuf[BLOCK / 64];
    const int wid = threadIdx.x >> 6;
    if ((threadIdx.x & 63) == 0) sbuf[wid] = local;
    __syncthreads();
    if (threadIdx.x == 0) {
        float s = 0.0f;
        #pragma unroll
        for (int i = 0; i < BLOCK / 64; ++i) s += sbuf[i];
        atomicAdd(ws, (double)s);
    }
}

__global__ void finalize_kernel(const double* __restrict__ ws,
                                float* __restrict__ out, double count)
{
    *out = (float)(*ws / count);
}

// ---- launch ----------------------------------------------------------------

extern "C" void kernel_launch(void* const* d_in, const int* in_sizes, int n_in,
                              void* d_out, int out_size, void* d_ws, size_t ws_size,
                              hipStream_t stream)
{
    const float* x  = (const float*)d_in[0];
    const int*  ei  = (const int*)d_in[1];
    const int*  nei = (const int*)d_in[2];
    const int E  = in_sizes[1] / 2;
    const int ND = in_sizes[0];          // N*D elements of x

    double* ws = (double*)d_ws;
    float* out = (float*)d_out;
    const double count = (double)E * (double)(KNEG + 1);

    const size_t need8 = 256 + (size_t)ND;   // 1 byte per element
    if (ws_size >= need8) {
        int2* xq = (int2*)((char*)d_ws + 256);
        cvt_fp8_kernel<<<dim3(1024), dim3(BLOCK), 0, stream>>>(x, xq, ws, ND / 8);
        neg_loss_fp8<<<dim3(2048), dim3(BLOCK), 0, stream>>>(xq, ei, nei, ws, E);
    } else {
        zero_ws_kernel<<<dim3(1), dim3(1), 0, stream>>>(ws);
        neg_loss_f32<<<dim3(2048), dim3(BLOCK), 0, stream>>>(x, ei, nei, ws, E);
    }

    finalize_kernel<<<dim3(1), dim3(1), 0, stream>>>(ws, out, count);
}

// Round 7
// 87.140 us; speedup vs baseline: 1.8211x; 1.2097x over previous
//
#include <hip/hip_runtime.h>

#define D 128
#define KNEG 5
#define BLOCK 256

typedef float f2 __attribute__((ext_vector_type(2)));

// Device-pass-only HW fp8 builtin detection (host pass lacks amdgcn builtins;
// the launcher below does NOT depend on this macro).
#if defined(__HIP_DEVICE_COMPILE__)
#if __has_builtin(__builtin_amdgcn_cvt_pk_f32_fp8) && __has_builtin(__builtin_amdgcn_cvt_pk_fp8_f32)
#define FP8_HW 1
#endif
#endif

// ---- fp8 e4m3fn software fallback (dead code when FP8_HW) ------------------

__device__ __forceinline__ float dec1_sw(unsigned b) {
    const unsigned s = b >> 7, e = (b >> 3) & 15, m = b & 7;
    float mag;
    if (e == 0) {
        mag = (float)m * 0x1p-9f;
    } else {
        union { unsigned u; float f; } c;
        c.u = ((e + 120u) << 23) | (m << 20);
        mag = c.f;
    }
    return s ? -mag : mag;
}

__device__ __forceinline__ unsigned enc1_sw(float x) {
    union { float f; unsigned u; } c; c.f = x;
    const unsigned s = (c.u >> 31) << 7;
    float a = fabsf(x);
    if (!(a >= 0x1p-10f)) return s;
    if (a < 0x1p-6f) {
        unsigned m = (unsigned)rintf(a * 512.0f);
        if (m > 7) return s | (1u << 3);
        return s | m;
    }
    c.f = a;
    unsigned bits = c.u + 0x00080000u;
    int e = (int)(bits >> 23) - 120;
    unsigned m = (bits >> 20) & 7;
    if (e >= 16) return s | 0x7Eu;
    if (e <= 0) return s | (1u << 3);
    return s | ((unsigned)e << 3) | m;
}

// ---- fp8 pack/unpack (HW when available) -----------------------------------

__device__ __forceinline__ void cvt8(int2 w, f2& a, f2& b, f2& c, f2& d) {
#ifdef FP8_HW
    a = __builtin_amdgcn_cvt_pk_f32_fp8(w.x, false);
    b = __builtin_amdgcn_cvt_pk_f32_fp8(w.x, true);
    c = __builtin_amdgcn_cvt_pk_f32_fp8(w.y, false);
    d = __builtin_amdgcn_cvt_pk_f32_fp8(w.y, true);
#else
    a[0] = dec1_sw(w.x & 0xff);         a[1] = dec1_sw((w.x >> 8) & 0xff);
    b[0] = dec1_sw((w.x >> 16) & 0xff); b[1] = dec1_sw((unsigned)w.x >> 24);
    c[0] = dec1_sw(w.y & 0xff);         c[1] = dec1_sw((w.y >> 8) & 0xff);
    d[0] = dec1_sw((w.y >> 16) & 0xff); d[1] = dec1_sw((unsigned)w.y >> 24);
#endif
}

__device__ __forceinline__ int pack4(float x, float y, float z, float w) {
#ifdef FP8_HW
    int r = 0;
    r = __builtin_amdgcn_cvt_pk_fp8_f32(x, y, r, false);
    r = __builtin_amdgcn_cvt_pk_fp8_f32(z, w, r, true);
    return r;
#else
    return (int)(enc1_sw(x) | (enc1_sw(y) << 8) | (enc1_sw(z) << 16) | (enc1_sw(w) << 24));
#endif
}

// ---- misc helpers ----------------------------------------------------------

// stable fast softplus: max(z,0) + log(1+exp(-|z|)); exp arg <= 0, log arg in (1,2]
__device__ __forceinline__ float softplus_fast(float z) {
    return fmaxf(z, 0.0f) + __logf(1.0f + __expf(-fabsf(z)));
}

__device__ __forceinline__ float dot8q(f2 v01, f2 v23, f2 v45, f2 v67, int2 w) {
    f2 b01, b23, b45, b67;
    cvt8(w, b01, b23, b45, b67);
    float s0 = v01[0] * b01[0];
    float s1 = v01[1] * b01[1];
    s0 = fmaf(v23[0], b23[0], s0);
    s1 = fmaf(v23[1], b23[1], s1);
    s0 = fmaf(v45[0], b45[0], s0);
    s1 = fmaf(v45[1], b45[1], s1);
    s0 = fmaf(v67[0], b67[0], s0);
    s1 = fmaf(v67[1], b67[1], s1);
    return s0 + s1;
}

// ---- kernels ---------------------------------------------------------------

__global__ void zero_ws_kernel(double* ws) { *ws = 0.0; }

// fp32 -> fp8 e4m3 row compression; 8 elements/thread; also zeroes the accumulator
__global__ __launch_bounds__(BLOCK) void cvt_fp8_kernel(const float* __restrict__ x,
                                                        int2* __restrict__ xq,
                                                        double* __restrict__ ws, int n8)
{
    if (blockIdx.x == 0 && threadIdx.x == 0) *ws = 0.0;
    int i = blockIdx.x * BLOCK + threadIdx.x;
    const int stride = gridDim.x * BLOCK;
    for (; i < n8; i += stride) {
        const float4* p = reinterpret_cast<const float4*>(x) + 2 * (size_t)i;
        const float4 f0 = p[0], f1 = p[1];
        int2 o;
        o.x = pack4(f0.x, f0.y, f0.z, f0.w);
        o.y = pack4(f1.x, f1.y, f1.z, f1.w);
        xq[i] = o;
    }
}

// main kernel, fp8 rows, software-pipelined:
// 16 lanes/edge, lane holds 8 cols (8 B); row = one 128 B line.
// Stage s+1's 7 row-gathers are issued before stage s's compute; indices are
// prefetched one further stage ahead so idx->gather never stalls.
__global__ __launch_bounds__(BLOCK) void neg_loss_fp8(
    const int2* __restrict__ xq,    // [N, 16] int2; row = 128 B
    const int* __restrict__ ei,     // [2, E]
    const int* __restrict__ nei,    // [K, E]
    double* __restrict__ ws, int E)
{
    const int l    = threadIdx.x & 15;
    const int grp  = blockIdx.x * (BLOCK / 16) + (threadIdx.x >> 4);
    const int ngrp = gridDim.x * (BLOCK / 16);

    float local = 0.0f;

    int e = grp;
    if (e < E) {
        // ---- prologue: indices + rows for the first edge, indices for the 2nd
        int js = ei[e];
        int j0 = ei[(size_t)E + e];
        int j1 = nei[e];
        int j2 = nei[(size_t)E * 1 + e];
        int j3 = nei[(size_t)E * 2 + e];
        int j4 = nei[(size_t)E * 3 + e];
        int j5 = nei[(size_t)E * 4 + e];

        int2 cv = xq[(size_t)js * 16 + l];
        int2 c0 = xq[(size_t)j0 * 16 + l];
        int2 c1 = xq[(size_t)j1 * 16 + l];
        int2 c2 = xq[(size_t)j2 * 16 + l];
        int2 c3 = xq[(size_t)j3 * 16 + l];
        int2 c4 = xq[(size_t)j4 * 16 + l];
        int2 c5 = xq[(size_t)j5 * 16 + l];

        {
            const int e1 = e + ngrp;
            const int ep = (e1 < E) ? e1 : e;
            js = ei[ep];
            j0 = ei[(size_t)E + ep];
            j1 = nei[ep];
            j2 = nei[(size_t)E * 1 + ep];
            j3 = nei[(size_t)E * 2 + ep];
            j4 = nei[(size_t)E * 3 + ep];
            j5 = nei[(size_t)E * 4 + ep];
        }

        for (;;) {
            // ---- issue next stage's 7 row-gathers (addresses ready, no stall)
            const int2 nv = xq[(size_t)js * 16 + l];
            const int2 n0 = xq[(size_t)j0 * 16 + l];
            const int2 n1 = xq[(size_t)j1 * 16 + l];
            const int2 n2 = xq[(size_t)j2 * 16 + l];
            const int2 n3 = xq[(size_t)j3 * 16 + l];
            const int2 n4 = xq[(size_t)j4 * 16 + l];
            const int2 n5 = xq[(size_t)j5 * 16 + l];

            // ---- prefetch indices two stages ahead
            {
                const int e2 = e + 2 * ngrp;
                const int ep = (e2 < E) ? e2 : e;
                js = ei[ep];
                j0 = ei[(size_t)E + ep];
                j1 = nei[ep];
                j2 = nei[(size_t)E * 1 + ep];
                j3 = nei[(size_t)E * 2 + ep];
                j4 = nei[(size_t)E * 3 + ep];
                j5 = nei[(size_t)E * 4 + ep];
            }

            // ---- compute current stage (waits only on c*'s loads)
            f2 v01, v23, v45, v67;
            cvt8(cv, v01, v23, v45, v67);   // src slice decoded once, reused 6x

            float a0 = dot8q(v01, v23, v45, v67, c0);
            float a1 = dot8q(v01, v23, v45, v67, c1);
            float a2 = dot8q(v01, v23, v45, v67, c2);
            float a3 = dot8q(v01, v23, v45, v67, c3);
            float a4 = dot8q(v01, v23, v45, v67, c4);
            float a5 = dot8q(v01, v23, v45, v67, c5);

            // butterfly over the 16-lane group (xor masks <16 stay in-group)
            #pragma unroll
            for (int off = 8; off > 0; off >>= 1) {
                a0 += __shfl_xor(a0, off);
                a1 += __shfl_xor(a1, off);
                a2 += __shfl_xor(a2, off);
                a3 += __shfl_xor(a3, off);
                a4 += __shfl_xor(a4, off);
                a5 += __shfl_xor(a5, off);
            }

            // lanes 0-5 each take one softplus term; positive logit: softplus(-z)
            float z = -a0;
            if (l == 1) z = a1;
            else if (l == 2) z = a2;
            else if (l == 3) z = a3;
            else if (l == 4) z = a4;
            else if (l == 5) z = a5;
            if (l < 6) local += softplus_fast(z);

            e += ngrp;
            if (e >= E) break;

            // ---- rotate buffers
            cv = nv; c0 = n0; c1 = n1; c2 = n2; c3 = n3; c4 = n4; c5 = n5;
        }
    }

    #pragma unroll
    for (int off = 32; off > 0; off >>= 1) local += __shfl_xor(local, off);

    __shared__ float sbuf[BLOCK / 64];
    const int wid = threadIdx.x >> 6;
    if ((threadIdx.x & 63) == 0) sbuf[wid] = local;
    __syncthreads();
    if (threadIdx.x == 0) {
        float s = 0.0f;
        #pragma unroll
        for (int i = 0; i < BLOCK / 64; ++i) s += sbuf[i];
        atomicAdd(ws, (double)s);
    }
}

// fp32 fallback (only if ws can't hold the 12.8 MB fp8 table)
__global__ __launch_bounds__(BLOCK) void neg_loss_f32(
    const float* __restrict__ x,
    const int* __restrict__ ei,
    const int* __restrict__ nei,
    double* __restrict__ ws, int E)
{
    const int l    = threadIdx.x & 31;
    const int grp  = blockIdx.x * (BLOCK / 32) + (threadIdx.x >> 5);
    const int ngrp = gridDim.x * (BLOCK / 32);
    const int colb = l * 4;

    float local = 0.0f;

    for (int e = grp; e < E; e += ngrp) {
        const int src = ei[e];
        const int idx[6] = {ei[E + e], nei[e],
                            nei[(size_t)E * 1 + e], nei[(size_t)E * 2 + e],
                            nei[(size_t)E * 3 + e], nei[(size_t)E * 4 + e]};

        const float4 vi = *reinterpret_cast<const float4*>(x + (size_t)src * D + colb);
        float a[6];
        #pragma unroll
        for (int n = 0; n < 6; ++n) {
            const float4 u = *reinterpret_cast<const float4*>(x + (size_t)idx[n] * D + colb);
            a[n] = fmaf(vi.x, u.x, fmaf(vi.y, u.y, fmaf(vi.z, u.z, vi.w * u.w)));
        }

        #pragma unroll
        for (int off = 16; off > 0; off >>= 1) {
            #pragma unroll
            for (int n = 0; n < 6; ++n) a[n] += __shfl_xor(a[n], off);
        }

        float z = -a[0];
        if (l == 1) z = a[1];
        else if (l == 2) z = a[2];
        else if (l == 3) z = a[3];
        else if (l == 4) z = a[4];
        else if (l == 5) z = a[5];
        if (l < 6) local += softplus_fast(z);
    }

    #pragma unroll
    for (int off = 32; off > 0; off >>= 1) local += __shfl_xor(local, off);

    __shared__ float sbuf[BLOCK / 64];
    const int wid = threadIdx.x >> 6;
    if ((threadIdx.x & 63) == 0) sbuf[wid] = local;
    __syncthreads();
    if (threadIdx.x == 0) {
        float s = 0.0f;
        #pragma unroll
        for (int i = 0; i < BLOCK / 64; ++i) s += sbuf[i];
        atomicAdd(ws, (double)s);
    }
}

__global__ void finalize_kernel(const double* __restrict__ ws,
                                float* __restrict__ out, double count)
{
    *out = (float)(*ws / count);
}

// ---- launch ----------------------------------------------------------------

extern "C" void kernel_launch(void* const* d_in, const int* in_sizes, int n_in,
                              void* d_out, int out_size, void* d_ws, size_t ws_size,
                              hipStream_t stream)
{
    const float* x  = (const float*)d_in[0];
    const int*  ei  = (const int*)d_in[1];
    const int*  nei = (const int*)d_in[2];
    const int E  = in_sizes[1] / 2;
    const int ND = in_sizes[0];          // N*D elements of x

    double* ws = (double*)d_ws;
    float* out = (float*)d_out;
    const double count = (double)E * (double)(KNEG + 1);

    const size_t need8 = 256 + (size_t)ND;   // 1 byte per element
    if (ws_size >= need8) {
        int2* xq = (int2*)((char*)d_ws + 256);
        cvt_fp8_kernel<<<dim3(1024), dim3(BLOCK), 0, stream>>>(x, xq, ws, ND / 8);
        neg_loss_fp8<<<dim3(2048), dim3(BLOCK), 0, stream>>>(xq, ei, nei, ws, E);
    } else {
        zero_ws_kernel<<<dim3(1), dim3(1), 0, stream>>>(ws);
        neg_loss_f32<<<dim3(2048), dim3(BLOCK), 0, stream>>>(x, ei, nei, ws, E);
    }

    finalize_kernel<<<dim3(1), dim3(1), 0, stream>>>(ws, out, count);
}

// Round 8
// 80.556 us; speedup vs baseline: 1.9700x; 1.0817x over previous
//
#include <hip/hip_runtime.h>

#define D 128
#define KNEG 5
#define BLOCK 256

typedef float f2 __attribute__((ext_vector_type(2)));

// Device-pass-only HW fp8 builtin detection (host pass lacks amdgcn builtins;
// the launcher below does NOT depend on this macro).
#if defined(__HIP_DEVICE_COMPILE__)
#if __has_builtin(__builtin_amdgcn_cvt_pk_f32_fp8) && __has_builtin(__builtin_amdgcn_cvt_pk_fp8_f32)
#define FP8_HW 1
#endif
#endif

// ---- fp8 e4m3fn software fallback (dead code when FP8_HW) ------------------

__device__ __forceinline__ float dec1_sw(unsigned b) {
    const unsigned s = b >> 7, e = (b >> 3) & 15, m = b & 7;
    float mag;
    if (e == 0) {
        mag = (float)m * 0x1p-9f;
    } else {
        union { unsigned u; float f; } c;
        c.u = ((e + 120u) << 23) | (m << 20);
        mag = c.f;
    }
    return s ? -mag : mag;
}

__device__ __forceinline__ unsigned enc1_sw(float x) {
    union { float f; unsigned u; } c; c.f = x;
    const unsigned s = (c.u >> 31) << 7;
    float a = fabsf(x);
    if (!(a >= 0x1p-10f)) return s;
    if (a < 0x1p-6f) {
        unsigned m = (unsigned)rintf(a * 512.0f);
        if (m > 7) return s | (1u << 3);
        return s | m;
    }
    c.f = a;
    unsigned bits = c.u + 0x00080000u;
    int e = (int)(bits >> 23) - 120;
    unsigned m = (bits >> 20) & 7;
    if (e >= 16) return s | 0x7Eu;
    if (e <= 0) return s | (1u << 3);
    return s | ((unsigned)e << 3) | m;
}

// ---- fp8 pack/unpack (HW when available) -----------------------------------

__device__ __forceinline__ void cvt8(int wx, int wy, f2& a, f2& b, f2& c, f2& d) {
#ifdef FP8_HW
    a = __builtin_amdgcn_cvt_pk_f32_fp8(wx, false);
    b = __builtin_amdgcn_cvt_pk_f32_fp8(wx, true);
    c = __builtin_amdgcn_cvt_pk_f32_fp8(wy, false);
    d = __builtin_amdgcn_cvt_pk_f32_fp8(wy, true);
#else
    a[0] = dec1_sw(wx & 0xff);         a[1] = dec1_sw((wx >> 8) & 0xff);
    b[0] = dec1_sw((wx >> 16) & 0xff); b[1] = dec1_sw((unsigned)wx >> 24);
    c[0] = dec1_sw(wy & 0xff);         c[1] = dec1_sw((wy >> 8) & 0xff);
    d[0] = dec1_sw((wy >> 16) & 0xff); d[1] = dec1_sw((unsigned)wy >> 24);
#endif
}

__device__ __forceinline__ int pack4(float x, float y, float z, float w) {
#ifdef FP8_HW
    int r = 0;
    r = __builtin_amdgcn_cvt_pk_fp8_f32(x, y, r, false);
    r = __builtin_amdgcn_cvt_pk_fp8_f32(z, w, r, true);
    return r;
#else
    return (int)(enc1_sw(x) | (enc1_sw(y) << 8) | (enc1_sw(z) << 16) | (enc1_sw(w) << 24));
#endif
}

// ---- misc helpers ----------------------------------------------------------

// stable fast softplus: max(z,0) + log(1+exp(-|z|)); exp arg <= 0, log arg in (1,2]
__device__ __forceinline__ float softplus_fast(float z) {
    return fmaxf(z, 0.0f) + __logf(1.0f + __expf(-fabsf(z)));
}

// decoded 16-column src slice (named members: compile-time indexed -> registers)
struct V16 { f2 v0, v1, v2, v3, v4, v5, v6, v7; };

__device__ __forceinline__ V16 dec16(int4 w) {
    V16 v;
    cvt8(w.x, w.y, v.v0, v.v1, v.v2, v.v3);
    cvt8(w.z, w.w, v.v4, v.v5, v.v6, v.v7);
    return v;
}

__device__ __forceinline__ float dot16q(const V16& v, int4 w) {
    f2 b0, b1, b2, b3, b4, b5, b6, b7;
    cvt8(w.x, w.y, b0, b1, b2, b3);
    cvt8(w.z, w.w, b4, b5, b6, b7);
    float s0 = v.v0[0] * b0[0];
    float s1 = v.v0[1] * b0[1];
    s0 = fmaf(v.v1[0], b1[0], s0);  s1 = fmaf(v.v1[1], b1[1], s1);
    s0 = fmaf(v.v2[0], b2[0], s0);  s1 = fmaf(v.v2[1], b2[1], s1);
    s0 = fmaf(v.v3[0], b3[0], s0);  s1 = fmaf(v.v3[1], b3[1], s1);
    s0 = fmaf(v.v4[0], b4[0], s0);  s1 = fmaf(v.v4[1], b4[1], s1);
    s0 = fmaf(v.v5[0], b5[0], s0);  s1 = fmaf(v.v5[1], b5[1], s1);
    s0 = fmaf(v.v6[0], b6[0], s0);  s1 = fmaf(v.v6[1], b6[1], s1);
    s0 = fmaf(v.v7[0], b7[0], s0);  s1 = fmaf(v.v7[1], b7[1], s1);
    return s0 + s1;
}

// ---- kernels ---------------------------------------------------------------

__global__ void zero_ws_kernel(double* ws) { *ws = 0.0; }

// fp32 -> fp8 e4m3 row compression; 16 elements/thread; also zeroes the accumulator
__global__ __launch_bounds__(BLOCK) void cvt_fp8_kernel(const float* __restrict__ x,
                                                        int4* __restrict__ xq,
                                                        double* __restrict__ ws, int n16)
{
    if (blockIdx.x == 0 && threadIdx.x == 0) *ws = 0.0;
    int i = blockIdx.x * BLOCK + threadIdx.x;
    const int stride = gridDim.x * BLOCK;
    for (; i < n16; i += stride) {
        const float4* p = reinterpret_cast<const float4*>(x) + 4 * (size_t)i;
        const float4 f0 = p[0], f1 = p[1], g0 = p[2], g1 = p[3];
        int4 o;
        o.x = pack4(f0.x, f0.y, f0.z, f0.w);
        o.y = pack4(f1.x, f1.y, f1.z, f1.w);
        o.z = pack4(g0.x, g0.y, g0.z, g0.w);
        o.w = pack4(g1.x, g1.y, g1.z, g1.w);
        xq[i] = o;
    }
}

// main kernel, fp8 rows, software-pipelined, 8 lanes/edge (8 edges/wave):
// lane holds 16 cols (one int4 = 16 B); row = one 128 B line.
// Stage s+1's 7 row-gathers are issued before stage s's compute; indices are
// prefetched one further stage ahead so idx->gather never stalls.
__global__ __launch_bounds__(BLOCK) void neg_loss_fp8(
    const int4* __restrict__ xq,    // [N, 8] int4; row = 128 B
    const int* __restrict__ ei,     // [2, E]
    const int* __restrict__ nei,    // [K, E]
    double* __restrict__ ws, int E)
{
    const int l    = threadIdx.x & 7;
    const int grp  = blockIdx.x * (BLOCK / 8) + (threadIdx.x >> 3);
    const int ngrp = gridDim.x * (BLOCK / 8);

    float local = 0.0f;

    int e = grp;
    if (e < E) {
        // ---- prologue: rows for the first edge; indices for the second
        int js = ei[e];
        int j0 = ei[(size_t)E + e];
        int j1 = nei[e];
        int j2 = nei[(size_t)E * 1 + e];
        int j3 = nei[(size_t)E * 2 + e];
        int j4 = nei[(size_t)E * 3 + e];
        int j5 = nei[(size_t)E * 4 + e];

        int4 cv = xq[(size_t)js * 8 + l];
        int4 c0 = xq[(size_t)j0 * 8 + l];
        int4 c1 = xq[(size_t)j1 * 8 + l];
        int4 c2 = xq[(size_t)j2 * 8 + l];
        int4 c3 = xq[(size_t)j3 * 8 + l];
        int4 c4 = xq[(size_t)j4 * 8 + l];
        int4 c5 = xq[(size_t)j5 * 8 + l];

        {
            const int e1 = e + ngrp;
            const int ep = (e1 < E) ? e1 : e;
            js = ei[ep];
            j0 = ei[(size_t)E + ep];
            j1 = nei[ep];
            j2 = nei[(size_t)E * 1 + ep];
            j3 = nei[(size_t)E * 2 + ep];
            j4 = nei[(size_t)E * 3 + ep];
            j5 = nei[(size_t)E * 4 + ep];
        }

        for (;;) {
            // ---- issue next stage's 7 row-gathers (addresses ready, no stall)
            const int4 nv = xq[(size_t)js * 8 + l];
            const int4 n0 = xq[(size_t)j0 * 8 + l];
            const int4 n1 = xq[(size_t)j1 * 8 + l];
            const int4 n2 = xq[(size_t)j2 * 8 + l];
            const int4 n3 = xq[(size_t)j3 * 8 + l];
            const int4 n4 = xq[(size_t)j4 * 8 + l];
            const int4 n5 = xq[(size_t)j5 * 8 + l];

            // ---- prefetch indices two stages ahead
            {
                const int e2 = e + 2 * ngrp;
                const int ep = (e2 < E) ? e2 : e;
                js = ei[ep];
                j0 = ei[(size_t)E + ep];
                j1 = nei[ep];
                j2 = nei[(size_t)E * 1 + ep];
                j3 = nei[(size_t)E * 2 + ep];
                j4 = nei[(size_t)E * 3 + ep];
                j5 = nei[(size_t)E * 4 + ep];
            }

            // ---- compute current stage (waits only on c*'s loads)
            const V16 v = dec16(cv);        // src slice decoded once, reused 6x

            float a0 = dot16q(v, c0);
            float a1 = dot16q(v, c1);
            float a2 = dot16q(v, c2);
            float a3 = dot16q(v, c3);
            float a4 = dot16q(v, c4);
            float a5 = dot16q(v, c5);

            // butterfly over the 8-lane group (xor masks <8 stay in-group)
            #pragma unroll
            for (int off = 4; off > 0; off >>= 1) {
                a0 += __shfl_xor(a0, off);
                a1 += __shfl_xor(a1, off);
                a2 += __shfl_xor(a2, off);
                a3 += __shfl_xor(a3, off);
                a4 += __shfl_xor(a4, off);
                a5 += __shfl_xor(a5, off);
            }

            // lanes 0-5 each take one softplus term; positive logit: softplus(-z)
            float z = -a0;
            if (l == 1) z = a1;
            else if (l == 2) z = a2;
            else if (l == 3) z = a3;
            else if (l == 4) z = a4;
            else if (l == 5) z = a5;
            if (l < 6) local += softplus_fast(z);

            e += ngrp;
            if (e >= E) break;

            // ---- rotate buffers
            cv = nv; c0 = n0; c1 = n1; c2 = n2; c3 = n3; c4 = n4; c5 = n5;
        }
    }

    #pragma unroll
    for (int off = 32; off > 0; off >>= 1) local += __shfl_xor(local, off);

    __shared__ float sbuf[BLOCK / 64];
    const int wid = threadIdx.x >> 6;
    if ((threadIdx.x & 63) == 0) sbuf[wid] = local;
    __syncthreads();
    if (threadIdx.x == 0) {
        float s = 0.0f;
        #pragma unroll
        for (int i = 0; i < BLOCK / 64; ++i) s += sbuf[i];
        atomicAdd(ws, (double)s);
    }
}

// fp32 fallback (only if ws can't hold the 12.8 MB fp8 table)
__global__ __launch_bounds__(BLOCK) void neg_loss_f32(
    const float* __restrict__ x,
    const int* __restrict__ ei,
    const int* __restrict__ nei,
    double* __restrict__ ws, int E)
{
    const int l    = threadIdx.x & 31;
    const int grp  = blockIdx.x * (BLOCK / 32) + (threadIdx.x >> 5);
    const int ngrp = gridDim.x * (BLOCK / 32);
    const int colb = l * 4;

    float local = 0.0f;

    for (int e = grp; e < E; e += ngrp) {
        const int src = ei[e];
        const int idx[6] = {ei[E + e], nei[e],
                            nei[(size_t)E * 1 + e], nei[(size_t)E * 2 + e],
                            nei[(size_t)E * 3 + e], nei[(size_t)E * 4 + e]};

        const float4 vi = *reinterpret_cast<const float4*>(x + (size_t)src * D + colb);
        float a[6];
        #pragma unroll
        for (int n = 0; n < 6; ++n) {
            const float4 u = *reinterpret_cast<const float4*>(x + (size_t)idx[n] * D + colb);
            a[n] = fmaf(vi.x, u.x, fmaf(vi.y, u.y, fmaf(vi.z, u.z, vi.w * u.w)));
        }

        #pragma unroll
        for (int off = 16; off > 0; off >>= 1) {
            #pragma unroll
            for (int n = 0; n < 6; ++n) a[n] += __shfl_xor(a[n], off);
        }

        float z = -a[0];
        if (l == 1) z = a[1];
        else if (l == 2) z = a[2];
        else if (l == 3) z = a[3];
        else if (l == 4) z = a[4];
        else if (l == 5) z = a[5];
        if (l < 6) local += softplus_fast(z);
    }

    #pragma unroll
    for (int off = 32; off > 0; off >>= 1) local += __shfl_xor(local, off);

    __shared__ float sbuf[BLOCK / 64];
    const int wid = threadIdx.x >> 6;
    if ((threadIdx.x & 63) == 0) sbuf[wid] = local;
    __syncthreads();
    if (threadIdx.x == 0) {
        float s = 0.0f;
        #pragma unroll
        for (int i = 0; i < BLOCK / 64; ++i) s += sbuf[i];
        atomicAdd(ws, (double)s);
    }
}

__global__ void finalize_kernel(const double* __restrict__ ws,
                                float* __restrict__ out, double count)
{
    *out = (float)(*ws / count);
}

// ---- launch ----------------------------------------------------------------

extern "C" void kernel_launch(void* const* d_in, const int* in_sizes, int n_in,
                              void* d_out, int out_size, void* d_ws, size_t ws_size,
                              hipStream_t stream)
{
    const float* x  = (const float*)d_in[0];
    const int*  ei  = (const int*)d_in[1];
    const int*  nei = (const int*)d_in[2];
    const int E  = in_sizes[1] / 2;
    const int ND = in_sizes[0];          // N*D elements of x

    double* ws = (double*)d_ws;
    float* out = (float*)d_out;
    const double count = (double)E * (double)(KNEG + 1);

    const size_t need8 = 256 + (size_t)ND;   // 1 byte per element
    if (ws_size >= need8) {
        int4* xq = (int4*)((char*)d_ws + 256);
        cvt_fp8_kernel<<<dim3(2048), dim3(BLOCK), 0, stream>>>(x, xq, ws, ND / 16);
        neg_loss_fp8<<<dim3(2048), dim3(BLOCK), 0, stream>>>(xq, ei, nei, ws, E);
    } else {
        zero_ws_kernel<<<dim3(1), dim3(1), 0, stream>>>(ws);
        neg_loss_f32<<<dim3(2048), dim3(BLOCK), 0, stream>>>(x, ei, nei, ws, E);
    }

    finalize_kernel<<<dim3(1), dim3(1), 0, stream>>>(ws, out, count);
}